// Round 9
// baseline (174.450 us; speedup 1.0000x reference)
//
#include <hip/hip_runtime.h>

// LinearAttention: B=2, L=2048, D=1024, H=16, d=64.
// cvt_all ; QKV GEMM (BK=32) ; kv_local (MFMA + vTg export) ;
// attn_chunk (R7 structure + folded prefix) ; out GEMM (BK=32).
// Locked: BK=32 identity glds16 staging (R5/R6); within-row XOR swizzle free
// (R3/R4); S/B-fragments must be LDS-staged coalesced, NOT scattered-global
// (R8 regression); clock-normalize sessions via gemm_bt replay hbm_gbps (R7).

#define DEV __device__ __forceinline__

typedef __attribute__((ext_vector_type(8))) short bf16x8;
typedef __attribute__((ext_vector_type(4))) float f32x4;

DEV ushort f2bf(float f) {
  union { float f; unsigned u; } v; v.f = f;
  unsigned r = v.u + 0x7fffu + ((v.u >> 16) & 1u);
  return (ushort)(r >> 16);
}
DEV float bf2f(unsigned b) {
  union { unsigned u; float f; } v; v.u = (b & 0xffffu) << 16;
  return v.f;
}
DEV void glds16(const ushort* g, ushort* l) {
  __builtin_amdgcn_global_load_lds(
      (const __attribute__((address_space(1))) unsigned int*)g,
      (__attribute__((address_space(3))) unsigned int*)l, 16, 0, 0);
}

__global__ __launch_bounds__(256) void cvt_all(const float* __restrict__ x,
                                               const float* __restrict__ Ww,
                                               const float* __restrict__ Ow,
                                               ushort* __restrict__ xb,
                                               ushort* __restrict__ wqkvb,
                                               ushort* __restrict__ outwb) {
  int i = blockIdx.x * 256 + threadIdx.x;
  const float* src; ushort* dst; int off;
  if (i < 1048576)      { src = x;  dst = xb;    off = i; }
  else if (i < 1835008) { src = Ww; dst = wqkvb; off = i - 1048576; }
  else                  { src = Ow; dst = outwb; off = i - 1835008; }
  float4 v = ((const float4*)src)[off];
  ushort4 o;
  o.x = f2bf(v.x); o.y = f2bf(v.y); o.z = f2bf(v.z); o.w = f2bf(v.w);
  ((ushort4*)dst)[off] = o;
}

// QKV: C = A[4096,1024]*Bw[3072,1024]^T + bias ; 128x128x32, identity staging.
template <bool OUT_BF16, bool KSCALE>
__global__ __launch_bounds__(256) void gemm_bt(const ushort* __restrict__ A,
                                               const ushort* __restrict__ Bw,
                                               const float* __restrict__ bias,
                                               void* __restrict__ Cout,
                                               int M, int N, int K) {
  __shared__ ushort As[128 * 32];
  __shared__ ushort Bs[128 * 32];
  const int t = threadIdx.x;
  const int wid = t >> 6, lane = t & 63;
  const int quad = lane >> 4, l16 = lane & 15;
  const int g = blockIdx.x;            // 768 = 8 XCD * 96
  const int j = g >> 3;
  const int bx = (g & 7) * 3 + j % 3;
  const int by = j / 3;
  const int bm = by * 128, bn = bx * 128;
  const int wm = (wid >> 1) * 64, wn = (wid & 1) * 64;

  f32x4 acc[4][4];
  const f32x4 z = {0.f, 0.f, 0.f, 0.f};
#pragma unroll
  for (int i = 0; i < 4; ++i)
#pragma unroll
    for (int jj = 0; jj < 4; ++jj) acc[i][jj] = z;

  const ushort* ag = A + (size_t)(bm + (t >> 2)) * K + ((t & 3) * 8);
  const ushort* bg = Bw + (size_t)(bn + (t >> 2)) * K + ((t & 3) * 8);
  ushort* asl = As + wid * 512;
  ushort* bsl = Bs + wid * 512;
  const size_t rowskip = (size_t)64 * K;

  for (int k0 = 0; k0 < K; k0 += 32) {
    glds16(ag + k0, asl);
    glds16(ag + k0 + rowskip, asl + 2048);
    glds16(bg + k0, bsl);
    glds16(bg + k0 + rowskip, bsl + 2048);
    __syncthreads();
    bf16x8 af[4], bf[4];
#pragma unroll
    for (int i = 0; i < 4; ++i) {
      af[i] = *(const bf16x8*)(As + (wm + i * 16 + l16) * 32 + quad * 8);
      bf[i] = *(const bf16x8*)(Bs + (wn + i * 16 + l16) * 32 + quad * 8);
    }
#pragma unroll
    for (int i = 0; i < 4; ++i)
#pragma unroll
      for (int jj = 0; jj < 4; ++jj)
        acc[i][jj] = __builtin_amdgcn_mfma_f32_16x16x32_bf16(af[i], bf[jj], acc[i][jj], 0, 0, 0);
    __syncthreads();
  }

#pragma unroll
  for (int i = 0; i < 4; ++i)
#pragma unroll
    for (int jj = 0; jj < 4; ++jj) {
      const int col = bn + wn + jj * 16 + l16;
      const float bv = bias[col];
      float sc = 1.f;
      if (KSCALE) sc = ((col >> 10) == 1) ? 0.125f : 1.f;
#pragma unroll
      for (int r = 0; r < 4; ++r) {
        const int row = bm + wm + i * 16 + quad * 4 + r;
        const float v = (acc[i][jj][r] + bv) * sc;
        if (OUT_BF16)
          ((ushort*)Cout)[(size_t)row * N + col] = f2bf(v);
        else
          ((float*)Cout)[(size_t)row * N + col] = v;
      }
    }
}

// Out projection: BM=64, BN=128, BK=32; grid 512.
__global__ __launch_bounds__(256) void gemm_out64(const ushort* __restrict__ A,
                                                  const ushort* __restrict__ Bw,
                                                  const float* __restrict__ bias,
                                                  float* __restrict__ C,
                                                  int M, int N, int K) {
  __shared__ ushort As[64 * 32];
  __shared__ ushort Bs[128 * 32];
  const int t = threadIdx.x;
  const int wid = t >> 6, lane = t & 63;
  const int quad = lane >> 4, l16 = lane & 15;
  const int g = blockIdx.x;
  const int bm = (g >> 3) * 64, bn = (g & 7) * 128;
  const int wn = wid * 32;

  f32x4 acc[4][2];
  const f32x4 z = {0.f, 0.f, 0.f, 0.f};
#pragma unroll
  for (int i = 0; i < 4; ++i) { acc[i][0] = z; acc[i][1] = z; }

  const ushort* ag = A + (size_t)(bm + (t >> 2)) * K + ((t & 3) * 8);
  const ushort* bg = Bw + (size_t)(bn + (t >> 2)) * K + ((t & 3) * 8);
  ushort* asl = As + wid * 512;
  ushort* bsl = Bs + wid * 512;
  const size_t rowskip = (size_t)64 * K;

  for (int k0 = 0; k0 < K; k0 += 32) {
    glds16(ag + k0, asl);
    glds16(bg + k0, bsl);
    glds16(bg + k0 + rowskip, bsl + 2048);
    __syncthreads();
    bf16x8 af[4], bf[2];
#pragma unroll
    for (int i = 0; i < 4; ++i)
      af[i] = *(const bf16x8*)(As + (i * 16 + l16) * 32 + quad * 8);
#pragma unroll
    for (int jj = 0; jj < 2; ++jj)
      bf[jj] = *(const bf16x8*)(Bs + (wn + jj * 16 + l16) * 32 + quad * 8);
#pragma unroll
    for (int i = 0; i < 4; ++i)
#pragma unroll
      for (int jj = 0; jj < 2; ++jj)
        acc[i][jj] = __builtin_amdgcn_mfma_f32_16x16x32_bf16(af[i], bf[jj], acc[i][jj], 0, 0, 0);
    __syncthreads();
  }

#pragma unroll
  for (int i = 0; i < 4; ++i)
#pragma unroll
    for (int jj = 0; jj < 2; ++jj) {
      const int col = bn + wn + jj * 16 + l16;
      const float bv = bias[col];
#pragma unroll
      for (int r = 0; r < 4; ++r) {
        const int row = bm + i * 16 + quad * 4 + r;
        C[(size_t)row * N + col] = acc[i][jj][r] + bv;
      }
    }
}

// Per-(bh,chunk) KV sums via MFMA + vT export:
// mlocT[bh][c][e][f] = sum_s v[s][e]*k[s][f]; vTg[bh][c][e:64][s:128] bf16.
__global__ __launch_bounds__(256) void kv_local(const ushort* __restrict__ qkv,
                                                float* __restrict__ mlocT,
                                                ushort* __restrict__ vTg) {
  const int c = blockIdx.x, bh = blockIdx.y;
  const int b = bh >> 4, hd = bh & 15;
  const int t = threadIdx.x;
  const int wid = t >> 6, lane = t & 63;
  const int quad = lane >> 4, l16 = lane & 15;
  __shared__ ushort kT[64 * 136];
  __shared__ ushort vT[64 * 136];

  {
    const int row = t & 127;
    const int isv = t >> 7;
    const ushort* gp = qkv + (size_t)(b * 2048 + c * 128 + row) * 3072 +
                       1024 + isv * 1024 + hd * 64;
    ushort tmp[64];
#pragma unroll
    for (int q = 0; q < 8; ++q) *(uint4*)(tmp + q * 8) = *(const uint4*)(gp + q * 8);
    ushort* dst = isv ? vT : kT;
#pragma unroll
    for (int j = 0; j < 64; ++j) dst[j * 136 + row] = tmp[j];
  }
  __syncthreads();

  {  // export vT -> vTg (coalesced)
    const int row = t >> 2, seg = t & 3;
    const ushort* src = vT + row * 136 + seg * 32;
    ushort* dst = vTg + ((size_t)bh * 16 + c) * 8192 + row * 128 + seg * 32;
#pragma unroll
    for (int q = 0; q < 4; ++q)
      *(uint4*)(dst + q * 8) = *(const uint4*)(src + q * 8);
  }

  const f32x4 z = {0.f, 0.f, 0.f, 0.f};
  f32x4 acc[4];
#pragma unroll
  for (int ct = 0; ct < 4; ++ct) acc[ct] = z;
#pragma unroll
  for (int kc = 0; kc < 4; ++kc) {
    bf16x8 afr = *(const bf16x8*)(vT + (wid * 16 + l16) * 136 + kc * 32 + quad * 8);
#pragma unroll
    for (int ct = 0; ct < 4; ++ct) {
      bf16x8 bfr = *(const bf16x8*)(kT + (ct * 16 + l16) * 136 + kc * 32 + quad * 8);
      acc[ct] = __builtin_amdgcn_mfma_f32_16x16x32_bf16(afr, bfr, acc[ct], 0, 0, 0);
    }
  }

  float* outp = mlocT + ((size_t)bh * 16 + c) * 4096;
#pragma unroll
  for (int ct = 0; ct < 4; ++ct)
#pragma unroll
    for (int r = 0; r < 4; ++r)
      outp[(wid * 16 + quad * 4 + r) * 64 + ct * 16 + l16] = acc[ct][r];
}

// Per-(bh,chunk): P = tril(Q K^T) ; Y = P V + Q S_prefix.
// R7 structure (best measured) + prefix folded in: run[16] accumulated from
// mlocT (chunks < c) in registers, overlapping the Q/K glds16 DMA; sT written
// from registers (no statesT round-trip, no kv_prefix launch).
__global__ __launch_bounds__(256) void attn_chunk(const ushort* __restrict__ qkv,
                                                  const float* __restrict__ mlocT,
                                                  const ushort* __restrict__ vTg,
                                                  ushort* __restrict__ yb) {
  const int c = blockIdx.x, bh = blockIdx.y;
  const int b = bh >> 4, hd = bh & 15;
  const int l0 = c * 128;
  const int t = threadIdx.x;
  const int wid = t >> 6, lane = t & 63;
  const int quad = lane >> 4, l16 = lane & 15;

  __shared__ ushort P[16384];  // [row][16B chunks] XOR by row&7 ; later Y [row][72]
  __shared__ ushort U[16384];
  ushort* Qs = U;              // [row:128][64] chunk^(row&7)
  ushort* Ks = U + 8192;
  ushort* vT = U;              // phase2: [e:64][s:128], chunk^(e&7)
  ushort* sT = U + 8704;       // phase2: [e:64][f:64] stride 72

  {  // zero P
    uint4 zz; zz.x = zz.y = zz.z = zz.w = 0u;
    uint4* p4 = (uint4*)P;
#pragma unroll
    for (int i = 0; i < 8; ++i) p4[i * 256 + t] = zz;
  }
  {  // stage Q,K swizzled
    const int kcs = ((lane & 7) ^ (lane >> 3)) * 8;
    const ushort* qg = qkv + (size_t)(b * 2048 + l0 + (t >> 3)) * 3072 + hd * 64 + kcs;
    ushort* ql = Qs + wid * 512;
    ushort* kl = Ks + wid * 512;
#pragma unroll
    for (int h2 = 0; h2 < 4; ++h2) {
      glds16(qg + (size_t)h2 * 32 * 3072, ql + h2 * 2048);
      glds16(qg + (size_t)h2 * 32 * 3072 + 1024, kl + h2 * 2048);
    }
  }

  // folded prefix: run[16] = sum over chunks < c of mlocT (overlaps DMA above)
  float run[16];
#pragma unroll
  for (int j = 0; j < 16; ++j) run[j] = 0.f;
  {
    const float4* mb = (const float4*)mlocT + (size_t)bh * 16384 + (size_t)t * 4;
    for (int cp = 0; cp < c; ++cp) {
      const float4* mc = mb + (size_t)cp * 1024;
#pragma unroll
      for (int k = 0; k < 4; ++k) {
        const float4 m = mc[k];
        run[k * 4 + 0] += m.x; run[k * 4 + 1] += m.y;
        run[k * 4 + 2] += m.z; run[k * 4 + 3] += m.w;
      }
    }
  }
  __syncthreads();  // B1: Q,K landed

  bf16x8 qf[2][2];
#pragma unroll
  for (int i = 0; i < 2; ++i) {
    const int rt = (i == 0) ? wid : 7 - wid;
#pragma unroll
    for (int kc = 0; kc < 2; ++kc)
      qf[i][kc] = *(const bf16x8*)(Qs + (rt * 16 + l16) * 64 +
                                   (((kc * 4 + quad) ^ (l16 & 7)) * 8));
  }

  const f32x4 z4 = {0.f, 0.f, 0.f, 0.f};
  f32x4 pacc[2][8];
#pragma unroll
  for (int i = 0; i < 2; ++i)
#pragma unroll
    for (int jj = 0; jj < 8; ++jj) pacc[i][jj] = z4;

#pragma unroll
  for (int i = 0; i < 2; ++i) {
    const int rt = (i == 0) ? wid : 7 - wid;
#pragma unroll
    for (int tj = 0; tj < 8; ++tj) {
      if (tj <= rt) {
#pragma unroll
        for (int kc = 0; kc < 2; ++kc) {
          bf16x8 kfr = *(const bf16x8*)(Ks + (tj * 16 + l16) * 64 +
                                        (((kc * 4 + quad) ^ (l16 & 7)) * 8));
          pacc[i][tj] = __builtin_amdgcn_mfma_f32_16x16x32_bf16(qf[i][kc], kfr, pacc[i][tj], 0, 0, 0);
        }
      }
    }
  }
  __syncthreads();  // B2: phase-1 reads done; U reusable

  {  // stage V^T via glds16 from vTg (within-row XOR swizzle)
    const ushort* vgb = vTg + ((size_t)bh * 16 + c) * 8192;
#pragma unroll
    for (int h = 0; h < 4; ++h) {
      const int gch = (wid * 4 + h) * 64 + lane;
      const int e = gch >> 4;
      const int sc = (gch & 15) ^ (e & 7);
      glds16(vgb + e * 128 + sc * 8, vT + (wid * 4 + h) * 512);
    }
  }
#pragma unroll
  for (int i = 0; i < 2; ++i) {  // write masked P (XOR by row&7)
    const int rt = (i == 0) ? wid : 7 - wid;
#pragma unroll
    for (int tj = 0; tj < 8; ++tj) {
      if (tj <= rt) {
#pragma unroll
        for (int r = 0; r < 4; ++r) {
          const int row = rt * 16 + quad * 4 + r;
          const int scol = tj * 16 + l16;
          const float v = (scol <= row) ? pacc[i][tj][r] : 0.f;
          P[row * 128 + (((scol >> 3) ^ (row & 7)) * 8) + (scol & 7)] = f2bf(v);
        }
      }
    }
  }
  {  // state from registers -> sT [e][f] stride 72
#pragma unroll
    for (int j = 0; j < 16; ++j) {
      const int ef = t * 16 + j;
      sT[(ef >> 6) * 72 + (ef & 63)] = f2bf(run[j]);
    }
  }
  __syncthreads();  // B3: P, vT, sT ready

  f32x4 yacc[2][4];
#pragma unroll
  for (int i = 0; i < 2; ++i)
#pragma unroll
    for (int jj = 0; jj < 4; ++jj) yacc[i][jj] = z4;

#pragma unroll
  for (int i = 0; i < 2; ++i) {
    const int rt = (i == 0) ? wid : 7 - wid;
    const int kcmax = rt >> 1;
#pragma unroll
    for (int kc = 0; kc < 4; ++kc) {
      if (kc <= kcmax) {
        const int prow = rt * 16 + l16;
        bf16x8 pf;
        *(uint4*)&pf = *(const uint4*)(P + prow * 128 + (((kc * 4 + quad) ^ (prow & 7)) * 8));
#pragma unroll
        for (int ct = 0; ct < 4; ++ct) {
          const int e = ct * 16 + l16;
          bf16x8 vf = *(const bf16x8*)(vT + e * 128 + (((kc * 4 + quad) ^ (e & 7)) * 8));
          yacc[i][ct] = __builtin_amdgcn_mfma_f32_16x16x32_bf16(pf, vf, yacc[i][ct], 0, 0, 0);
        }
      }
    }
#pragma unroll
    for (int kc = 0; kc < 2; ++kc) {
#pragma unroll
      for (int ct = 0; ct < 4; ++ct) {
        bf16x8 sf = *(const bf16x8*)(sT + (ct * 16 + l16) * 72 + kc * 32 + quad * 8);
        yacc[i][ct] = __builtin_amdgcn_mfma_f32_16x16x32_bf16(qf[i][kc], sf, yacc[i][ct], 0, 0, 0);
      }
    }
  }
  __syncthreads();  // B4: P reads done; reuse P as Y buffer

#pragma unroll
  for (int i = 0; i < 2; ++i) {  // Y -> LDS [row:128][64] stride 72
    const int rt = (i == 0) ? wid : 7 - wid;
#pragma unroll
    for (int ct = 0; ct < 4; ++ct)
#pragma unroll
      for (int r = 0; r < 4; ++r)
        P[(rt * 16 + quad * 4 + r) * 72 + ct * 16 + l16] = f2bf(yacc[i][ct][r]);
  }
  __syncthreads();  // B5

  {  // coalesced Y store
    const int row = t >> 1, seg = t & 1;
    const ushort* src = P + row * 72 + seg * 32;
    ushort* dst = yb + (size_t)(b * 2048 + l0 + row) * 1024 + hd * 64 + seg * 32;
#pragma unroll
    for (int q = 0; q < 4; ++q)
      *(uint4*)(dst + q * 8) = *(const uint4*)(src + q * 8);
  }
}

extern "C" void kernel_launch(void* const* d_in, const int* in_sizes, int n_in,
                              void* d_out, int out_size, void* d_ws, size_t ws_size,
                              hipStream_t stream) {
  const float* x  = (const float*)d_in[0];
  const float* Ww = (const float*)d_in[1];
  const float* Wb = (const float*)d_in[2];
  const float* Ow = (const float*)d_in[3];
  const float* Ob = (const float*)d_in[4];
  float* out = (float*)d_out;

  char* ws = (char*)d_ws;
  ushort* xb      = (ushort*)(ws);                              // dead after QKV GEMM
  ushort* vTg     = (ushort*)(ws);                              // reuses xb region
  ushort* wqkvb   = (ushort*)(ws + (size_t)8  * 1024 * 1024);
  ushort* outwb   = (ushort*)(ws + (size_t)14 * 1024 * 1024);
  ushort* qkvb    = (ushort*)(ws + (size_t)16 * 1024 * 1024);
  float*  mlocT   = (float*) (ws + (size_t)40 * 1024 * 1024);
  ushort* yb      = (ushort*)(ws + (size_t)52 * 1024 * 1024);

  cvt_all<<<8192, 256, 0, stream>>>(x, Ww, Ow, xb, wqkvb, outwb);
  gemm_bt<true, true><<<768, 256, 0, stream>>>(xb, wqkvb, Wb, (void*)qkvb, 4096, 3072, 1024);
  kv_local<<<dim3(16, 32), 256, 0, stream>>>(qkvb, mlocT, vTg);
  attn_chunk<<<dim3(16, 32), 256, 0, stream>>>(qkvb, mlocT, vTg, yb);
  gemm_out64<<<512, 256, 0, stream>>>(yb, outwb, Ob, out, 4096, 1024, 1024);
}

// Round 10
// 169.674 us; speedup vs baseline: 1.0281x; 1.0281x over previous
//
#include <hip/hip_runtime.h>

// LinearAttention: B=2, L=2048, D=1024, H=16, d=64.
// cvt_all ; QKV GEMM (BK=32, LDS-transposed epilogue) ; kv_local (MFMA+vTg) ;
// kv_prefix (split — fold regressed twice R4/R9) ; attn_chunk (R7 form) ;
// out GEMM (LDS-transposed fp32 epilogue).
// Locked: BK=32 identity glds16 staging (R5/R6); within-run XOR swizzle free
// (R3/R4); B-fragments must be LDS-staged, not scattered-global (R8);
// scalar-store epilogues cost ~20us -> wave-private LDS transpose (R10).

#define DEV __device__ __forceinline__

typedef __attribute__((ext_vector_type(8))) short bf16x8;
typedef __attribute__((ext_vector_type(4))) float f32x4;

DEV ushort f2bf(float f) {
  union { float f; unsigned u; } v; v.f = f;
  unsigned r = v.u + 0x7fffu + ((v.u >> 16) & 1u);
  return (ushort)(r >> 16);
}
DEV float bf2f(unsigned b) {
  union { unsigned u; float f; } v; v.u = (b & 0xffffu) << 16;
  return v.f;
}
DEV void glds16(const ushort* g, ushort* l) {
  __builtin_amdgcn_global_load_lds(
      (const __attribute__((address_space(1))) unsigned int*)g,
      (__attribute__((address_space(3))) unsigned int*)l, 16, 0, 0);
}

__global__ __launch_bounds__(256) void cvt_all(const float* __restrict__ x,
                                               const float* __restrict__ Ww,
                                               const float* __restrict__ Ow,
                                               ushort* __restrict__ xb,
                                               ushort* __restrict__ wqkvb,
                                               ushort* __restrict__ outwb) {
  int i = blockIdx.x * 256 + threadIdx.x;
  const float* src; ushort* dst; int off;
  if (i < 1048576)      { src = x;  dst = xb;    off = i; }
  else if (i < 1835008) { src = Ww; dst = wqkvb; off = i - 1048576; }
  else                  { src = Ow; dst = outwb; off = i - 1835008; }
  float4 v = ((const float4*)src)[off];
  ushort4 o;
  o.x = f2bf(v.x); o.y = f2bf(v.y); o.z = f2bf(v.z); o.w = f2bf(v.w);
  ((ushort4*)dst)[off] = o;
}

// QKV: C = A[4096,1024]*Bw[3072,1024]^T + bias ; 128x128x32, identity staging.
// Epilogue: per-wave LDS slab (16rows x 72) -> coalesced dwordx4 stores.
template <bool OUT_BF16, bool KSCALE>
__global__ __launch_bounds__(256) void gemm_bt(const ushort* __restrict__ A,
                                               const ushort* __restrict__ Bw,
                                               const float* __restrict__ bias,
                                               void* __restrict__ Cout,
                                               int M, int N, int K) {
  __shared__ ushort smem[8192];     // As[0..4095], Bs[4096..8191]; epilogue slabs
  ushort* As = smem;
  ushort* Bs = smem + 4096;
  const int t = threadIdx.x;
  const int wid = t >> 6, lane = t & 63;
  const int quad = lane >> 4, l16 = lane & 15;
  const int g = blockIdx.x;            // 768 = 8 XCD * 96
  const int j = g >> 3;
  const int bx = (g & 7) * 3 + j % 3;
  const int by = j / 3;
  const int bm = by * 128, bn = bx * 128;
  const int wm = (wid >> 1) * 64, wn = (wid & 1) * 64;

  f32x4 acc[4][4];
  const f32x4 z = {0.f, 0.f, 0.f, 0.f};
#pragma unroll
  for (int i = 0; i < 4; ++i)
#pragma unroll
    for (int jj = 0; jj < 4; ++jj) acc[i][jj] = z;

  const ushort* ag = A + (size_t)(bm + (t >> 2)) * K + ((t & 3) * 8);
  const ushort* bg = Bw + (size_t)(bn + (t >> 2)) * K + ((t & 3) * 8);
  ushort* asl = As + wid * 512;
  ushort* bsl = Bs + wid * 512;
  const size_t rowskip = (size_t)64 * K;

  for (int k0 = 0; k0 < K; k0 += 32) {
    glds16(ag + k0, asl);
    glds16(ag + k0 + rowskip, asl + 2048);
    glds16(bg + k0, bsl);
    glds16(bg + k0 + rowskip, bsl + 2048);
    __syncthreads();
    bf16x8 af[4], bf[4];
#pragma unroll
    for (int i = 0; i < 4; ++i) {
      af[i] = *(const bf16x8*)(As + (wm + i * 16 + l16) * 32 + quad * 8);
      bf[i] = *(const bf16x8*)(Bs + (wn + i * 16 + l16) * 32 + quad * 8);
    }
#pragma unroll
    for (int i = 0; i < 4; ++i)
#pragma unroll
      for (int jj = 0; jj < 4; ++jj)
        acc[i][jj] = __builtin_amdgcn_mfma_f32_16x16x32_bf16(af[i], bf[jj], acc[i][jj], 0, 0, 0);
    __syncthreads();
  }
  // after final barrier all staging reads are done -> smem reusable as slabs

  const int col0 = bn + wn;
  float bv[4], scl[4];
#pragma unroll
  for (int jj = 0; jj < 4; ++jj) {
    const int col = col0 + jj * 16 + l16;
    bv[jj] = bias[col];
    scl[jj] = KSCALE ? (((col >> 10) == 1) ? 0.125f : 1.f) : 1.f;
  }

  if (OUT_BF16) {
    ushort* slab = smem + wid * 1152;  // 16 x 72, wave-private
    const int row = lane >> 2, seg = lane & 3;
#pragma unroll
    for (int i = 0; i < 4; ++i) {
#pragma unroll
      for (int jj = 0; jj < 4; ++jj)
#pragma unroll
        for (int r = 0; r < 4; ++r)
          slab[(quad * 4 + r) * 72 + jj * 16 + l16] =
              f2bf((acc[i][jj][r] + bv[jj]) * scl[jj]);
      const ushort* src = slab + row * 72 + seg * 16;
      ushort* dst = (ushort*)Cout + (size_t)(bm + wm + i * 16 + row) * N + col0 + seg * 16;
      *(uint4*)(dst + 0) = *(const uint4*)(src + 0);
      *(uint4*)(dst + 8) = *(const uint4*)(src + 8);
    }
  } else {
#pragma unroll
    for (int i = 0; i < 4; ++i)
#pragma unroll
      for (int jj = 0; jj < 4; ++jj)
#pragma unroll
        for (int r = 0; r < 4; ++r)
          ((float*)Cout)[(size_t)(bm + wm + i * 16 + quad * 4 + r) * N + col0 + jj * 16 + l16] =
              (acc[i][jj][r] + bv[jj]) * scl[jj];
  }
}

// Out projection: BM=64, BN=128, BK=32; grid 512; fp32 LDS-transposed epilogue.
__global__ __launch_bounds__(256) void gemm_out64(const ushort* __restrict__ A,
                                                  const ushort* __restrict__ Bw,
                                                  const float* __restrict__ bias,
                                                  float* __restrict__ C,
                                                  int M, int N, int K) {
  __shared__ ushort smem[6144];     // As[0..2047], Bs[2048..6143]; fp32 slabs
  ushort* As = smem;
  ushort* Bs = smem + 2048;
  const int t = threadIdx.x;
  const int wid = t >> 6, lane = t & 63;
  const int quad = lane >> 4, l16 = lane & 15;
  const int g = blockIdx.x;
  const int bm = (g >> 3) * 64, bn = (g & 7) * 128;
  const int wn = wid * 32;

  f32x4 acc[4][2];
  const f32x4 z = {0.f, 0.f, 0.f, 0.f};
#pragma unroll
  for (int i = 0; i < 4; ++i) { acc[i][0] = z; acc[i][1] = z; }

  const ushort* ag = A + (size_t)(bm + (t >> 2)) * K + ((t & 3) * 8);
  const ushort* bg = Bw + (size_t)(bn + (t >> 2)) * K + ((t & 3) * 8);
  ushort* asl = As + wid * 512;
  ushort* bsl = Bs + wid * 512;
  const size_t rowskip = (size_t)64 * K;

  for (int k0 = 0; k0 < K; k0 += 32) {
    glds16(ag + k0, asl);
    glds16(bg + k0, bsl);
    glds16(bg + k0 + rowskip, bsl + 2048);
    __syncthreads();
    bf16x8 af[4], bf[2];
#pragma unroll
    for (int i = 0; i < 4; ++i)
      af[i] = *(const bf16x8*)(As + (i * 16 + l16) * 32 + quad * 8);
#pragma unroll
    for (int jj = 0; jj < 2; ++jj)
      bf[jj] = *(const bf16x8*)(Bs + (wn + jj * 16 + l16) * 32 + quad * 8);
#pragma unroll
    for (int i = 0; i < 4; ++i)
#pragma unroll
      for (int jj = 0; jj < 2; ++jj)
        acc[i][jj] = __builtin_amdgcn_mfma_f32_16x16x32_bf16(af[i], bf[jj], acc[i][jj], 0, 0, 0);
    __syncthreads();
  }

  float bv[2];
#pragma unroll
  for (int jj = 0; jj < 2; ++jj) bv[jj] = bias[bn + wn + jj * 16 + l16];

  float* fsl = (float*)smem + wid * 576;  // 16 x 36 floats, wave-private
  const int row = lane >> 2, seg = lane & 3;
#pragma unroll
  for (int i = 0; i < 4; ++i) {
#pragma unroll
    for (int jj = 0; jj < 2; ++jj)
#pragma unroll
      for (int r = 0; r < 4; ++r)
        fsl[(quad * 4 + r) * 36 + jj * 16 + l16] = acc[i][jj][r] + bv[jj];
    const float* src = fsl + row * 36 + seg * 8;
    float* dst = C + (size_t)(bm + i * 16 + row) * N + bn + wn + seg * 8;
    *(float4*)(dst + 0) = *(const float4*)(src + 0);
    *(float4*)(dst + 4) = *(const float4*)(src + 4);
  }
}

// Per-(bh,chunk) KV sums via MFMA + vT export:
// mlocT[bh][c][e][f] = sum_s v[s][e]*k[s][f]; vTg[bh][c][e:64][s:128] bf16.
__global__ __launch_bounds__(256) void kv_local(const ushort* __restrict__ qkv,
                                                float* __restrict__ mlocT,
                                                ushort* __restrict__ vTg) {
  const int c = blockIdx.x, bh = blockIdx.y;
  const int b = bh >> 4, hd = bh & 15;
  const int t = threadIdx.x;
  const int wid = t >> 6, lane = t & 63;
  const int quad = lane >> 4, l16 = lane & 15;
  __shared__ ushort kT[64 * 136];
  __shared__ ushort vT[64 * 136];

  {
    const int row = t & 127;
    const int isv = t >> 7;
    const ushort* gp = qkv + (size_t)(b * 2048 + c * 128 + row) * 3072 +
                       1024 + isv * 1024 + hd * 64;
    ushort tmp[64];
#pragma unroll
    for (int q = 0; q < 8; ++q) *(uint4*)(tmp + q * 8) = *(const uint4*)(gp + q * 8);
    ushort* dst = isv ? vT : kT;
#pragma unroll
    for (int j = 0; j < 64; ++j) dst[j * 136 + row] = tmp[j];
  }
  __syncthreads();

  {  // export vT -> vTg (coalesced)
    const int row = t >> 2, seg = t & 3;
    const ushort* src = vT + row * 136 + seg * 32;
    ushort* dst = vTg + ((size_t)bh * 16 + c) * 8192 + row * 128 + seg * 32;
#pragma unroll
    for (int q = 0; q < 4; ++q)
      *(uint4*)(dst + q * 8) = *(const uint4*)(src + q * 8);
  }

  const f32x4 z = {0.f, 0.f, 0.f, 0.f};
  f32x4 acc[4];
#pragma unroll
  for (int ct = 0; ct < 4; ++ct) acc[ct] = z;
#pragma unroll
  for (int kc = 0; kc < 4; ++kc) {
    bf16x8 afr = *(const bf16x8*)(vT + (wid * 16 + l16) * 136 + kc * 32 + quad * 8);
#pragma unroll
    for (int ct = 0; ct < 4; ++ct) {
      bf16x8 bfr = *(const bf16x8*)(kT + (ct * 16 + l16) * 136 + kc * 32 + quad * 8);
      acc[ct] = __builtin_amdgcn_mfma_f32_16x16x32_bf16(afr, bfr, acc[ct], 0, 0, 0);
    }
  }

  float* outp = mlocT + ((size_t)bh * 16 + c) * 4096;
#pragma unroll
  for (int ct = 0; ct < 4; ++ct)
#pragma unroll
    for (int r = 0; r < 4; ++r)
      outp[(wid * 16 + quad * 4 + r) * 64 + ct * 16 + l16] = acc[ct][r];
}

// Exclusive prefix over chunks, parallel over 4096 (e,f) entries per bh.
__global__ __launch_bounds__(256) void kv_prefix(const float* __restrict__ mlocT,
                                                 ushort* __restrict__ statesT) {
  const int slice = blockIdx.x, bh = blockIdx.y;
  const int eidx = slice * 256 + threadIdx.x;
  float run = 0.f;
  for (int c = 0; c < 16; ++c) {
    const size_t idx = ((size_t)bh * 16 + c) * 4096 + eidx;
    statesT[idx] = f2bf(run);
    run += mlocT[idx];
  }
}

// Per-(bh,chunk): P = tril(Q K^T) ; Y = P V + Q S_prefix. (R7 best-measured)
__global__ __launch_bounds__(256) void attn_chunk(const ushort* __restrict__ qkv,
                                                  const ushort* __restrict__ statesT,
                                                  const ushort* __restrict__ vTg,
                                                  ushort* __restrict__ yb) {
  const int c = blockIdx.x, bh = blockIdx.y;
  const int b = bh >> 4, hd = bh & 15;
  const int l0 = c * 128;
  const int t = threadIdx.x;
  const int wid = t >> 6, lane = t & 63;
  const int quad = lane >> 4, l16 = lane & 15;

  __shared__ ushort P[16384];
  __shared__ ushort U[16384];
  ushort* Qs = U;
  ushort* Ks = U + 8192;
  ushort* vT = U;               // phase2: [e:64][s:128], chunk^(e&7)
  ushort* sT = U + 8704;        // phase2: [e:64][f:64] stride 72

  {  // zero P
    uint4 zz; zz.x = zz.y = zz.z = zz.w = 0u;
    uint4* p4 = (uint4*)P;
#pragma unroll
    for (int i = 0; i < 8; ++i) p4[i * 256 + t] = zz;
  }
  {  // stage Q,K swizzled
    const int kcs = ((lane & 7) ^ (lane >> 3)) * 8;
    const ushort* qg = qkv + (size_t)(b * 2048 + l0 + (t >> 3)) * 3072 + hd * 64 + kcs;
    ushort* ql = Qs + wid * 512;
    ushort* kl = Ks + wid * 512;
#pragma unroll
    for (int h2 = 0; h2 < 4; ++h2) {
      glds16(qg + (size_t)h2 * 32 * 3072, ql + h2 * 2048);
      glds16(qg + (size_t)h2 * 32 * 3072 + 1024, kl + h2 * 2048);
    }
  }
  __syncthreads();

  bf16x8 qf[2][2];
#pragma unroll
  for (int i = 0; i < 2; ++i) {
    const int rt = (i == 0) ? wid : 7 - wid;
#pragma unroll
    for (int kc = 0; kc < 2; ++kc)
      qf[i][kc] = *(const bf16x8*)(Qs + (rt * 16 + l16) * 64 +
                                   (((kc * 4 + quad) ^ (l16 & 7)) * 8));
  }

  const f32x4 z4 = {0.f, 0.f, 0.f, 0.f};
  f32x4 pacc[2][8];
#pragma unroll
  for (int i = 0; i < 2; ++i)
#pragma unroll
    for (int jj = 0; jj < 8; ++jj) pacc[i][jj] = z4;

#pragma unroll
  for (int i = 0; i < 2; ++i) {
    const int rt = (i == 0) ? wid : 7 - wid;
#pragma unroll
    for (int tj = 0; tj < 8; ++tj) {
      if (tj <= rt) {
#pragma unroll
        for (int kc = 0; kc < 2; ++kc) {
          bf16x8 kfr = *(const bf16x8*)(Ks + (tj * 16 + l16) * 64 +
                                        (((kc * 4 + quad) ^ (l16 & 7)) * 8));
          pacc[i][tj] = __builtin_amdgcn_mfma_f32_16x16x32_bf16(qf[i][kc], kfr, pacc[i][tj], 0, 0, 0);
        }
      }
    }
  }
  __syncthreads();

  {  // stage V^T via glds16 from vTg
    const ushort* vgb = vTg + ((size_t)bh * 16 + c) * 8192;
#pragma unroll
    for (int h = 0; h < 4; ++h) {
      const int gch = (wid * 4 + h) * 64 + lane;
      const int e = gch >> 4;
      const int sc = (gch & 15) ^ (e & 7);
      glds16(vgb + e * 128 + sc * 8, vT + (wid * 4 + h) * 512);
    }
  }
#pragma unroll
  for (int i = 0; i < 2; ++i) {  // write masked P
    const int rt = (i == 0) ? wid : 7 - wid;
#pragma unroll
    for (int tj = 0; tj < 8; ++tj) {
      if (tj <= rt) {
#pragma unroll
        for (int r = 0; r < 4; ++r) {
          const int row = rt * 16 + quad * 4 + r;
          const int scol = tj * 16 + l16;
          const float v = (scol <= row) ? pacc[i][tj][r] : 0.f;
          P[row * 128 + (((scol >> 3) ^ (row & 7)) * 8) + (scol & 7)] = f2bf(v);
        }
      }
    }
  }
  {  // stage state coalesced -> sT stride 72
    const ushort* sg = statesT + ((size_t)bh * 16 + c) * 4096;
#pragma unroll
    for (int h = 0; h < 2; ++h) {
      const int cc = h * 256 + t;
      uint4 d = *(const uint4*)(sg + cc * 8);
      *(uint4*)(sT + (cc >> 3) * 72 + (cc & 7) * 8) = d;
    }
  }
  __syncthreads();

  f32x4 yacc[2][4];
#pragma unroll
  for (int i = 0; i < 2; ++i)
#pragma unroll
    for (int jj = 0; jj < 4; ++jj) yacc[i][jj] = z4;

#pragma unroll
  for (int i = 0; i < 2; ++i) {
    const int rt = (i == 0) ? wid : 7 - wid;
    const int kcmax = rt >> 1;
#pragma unroll
    for (int kc = 0; kc < 4; ++kc) {
      if (kc <= kcmax) {
        const int prow = rt * 16 + l16;
        bf16x8 pf;
        *(uint4*)&pf = *(const uint4*)(P + prow * 128 + (((kc * 4 + quad) ^ (prow & 7)) * 8));
#pragma unroll
        for (int ct = 0; ct < 4; ++ct) {
          const int e = ct * 16 + l16;
          bf16x8 vf = *(const bf16x8*)(vT + e * 128 + (((kc * 4 + quad) ^ (e & 7)) * 8));
          yacc[i][ct] = __builtin_amdgcn_mfma_f32_16x16x32_bf16(pf, vf, yacc[i][ct], 0, 0, 0);
        }
      }
    }
#pragma unroll
    for (int kc = 0; kc < 2; ++kc) {
#pragma unroll
      for (int ct = 0; ct < 4; ++ct) {
        bf16x8 sf = *(const bf16x8*)(sT + (ct * 16 + l16) * 72 + kc * 32 + quad * 8);
        yacc[i][ct] = __builtin_amdgcn_mfma_f32_16x16x32_bf16(qf[i][kc], sf, yacc[i][ct], 0, 0, 0);
      }
    }
  }
  __syncthreads();

#pragma unroll
  for (int i = 0; i < 2; ++i) {  // Y -> LDS [row:128][64] stride 72
    const int rt = (i == 0) ? wid : 7 - wid;
#pragma unroll
    for (int ct = 0; ct < 4; ++ct)
#pragma unroll
      for (int r = 0; r < 4; ++r)
        P[(rt * 16 + quad * 4 + r) * 72 + ct * 16 + l16] = f2bf(yacc[i][ct][r]);
  }
  __syncthreads();

  {  // coalesced Y store
    const int row = t >> 1, seg = t & 1;
    const ushort* src = P + row * 72 + seg * 32;
    ushort* dst = yb + (size_t)(b * 2048 + l0 + row) * 1024 + hd * 64 + seg * 32;
#pragma unroll
    for (int q = 0; q < 4; ++q)
      *(uint4*)(dst + q * 8) = *(const uint4*)(src + q * 8);
  }
}

extern "C" void kernel_launch(void* const* d_in, const int* in_sizes, int n_in,
                              void* d_out, int out_size, void* d_ws, size_t ws_size,
                              hipStream_t stream) {
  const float* x  = (const float*)d_in[0];
  const float* Ww = (const float*)d_in[1];
  const float* Wb = (const float*)d_in[2];
  const float* Ow = (const float*)d_in[3];
  const float* Ob = (const float*)d_in[4];
  float* out = (float*)d_out;

  char* ws = (char*)d_ws;
  ushort* xb      = (ushort*)(ws);                              // dead after QKV GEMM
  ushort* vTg     = (ushort*)(ws);                              // reuses xb region
  ushort* wqkvb   = (ushort*)(ws + (size_t)8  * 1024 * 1024);
  ushort* outwb   = (ushort*)(ws + (size_t)14 * 1024 * 1024);
  ushort* qkvb    = (ushort*)(ws + (size_t)16 * 1024 * 1024);
  float*  mlocT   = (float*) (ws + (size_t)40 * 1024 * 1024);
  ushort* statesT = (ushort*)(ws + (size_t)48 * 1024 * 1024);
  ushort* yb      = (ushort*)(ws + (size_t)52 * 1024 * 1024);

  cvt_all<<<8192, 256, 0, stream>>>(x, Ww, Ow, xb, wqkvb, outwb);
  gemm_bt<true, true><<<768, 256, 0, stream>>>(xb, wqkvb, Wb, (void*)qkvb, 4096, 3072, 1024);
  kv_local<<<dim3(16, 32), 256, 0, stream>>>(qkvb, mlocT, vTg);
  kv_prefix<<<dim3(16, 32), 256, 0, stream>>>(mlocT, statesT);
  attn_chunk<<<dim3(16, 32), 256, 0, stream>>>(qkvb, statesT, vTg, yb);
  gemm_out64<<<512, 256, 0, stream>>>(yb, outwb, Ob, out, 4096, 1024, 1024);
}

// Round 11
// 167.945 us; speedup vs baseline: 1.0387x; 1.0103x over previous
//
#include <hip/hip_runtime.h>

// LinearAttention: B=2, L=2048, D=1024, H=16, d=64.
// R7 configuration restored (best measured, ~156us normalized):
// cvt_all ; QKV GEMM (BK=32, scalar epilogue) ; kv_local (MFMA + vTg export) ;
// kv_prefix (split) ; attn_chunk (balanced waves, glds16 V, LDS-Y) ; out GEMM.
// Locked lessons: BK=32 identity glds16 staging (R5/R6); within-run XOR swizzle
// free (R3/R4); B-fragments LDS-staged not scattered-global (R8); prefix split
// (R4/R9); scalar global stores are fire-and-forget -> NO LDS-transpose
// epilogues (R10); zero-P prologue replaced by selective zero-write (tj<=rt|1).

#define DEV __device__ __forceinline__

typedef __attribute__((ext_vector_type(8))) short bf16x8;
typedef __attribute__((ext_vector_type(4))) float f32x4;

DEV ushort f2bf(float f) {
  union { float f; unsigned u; } v; v.f = f;
  unsigned r = v.u + 0x7fffu + ((v.u >> 16) & 1u);
  return (ushort)(r >> 16);
}
DEV float bf2f(unsigned b) {
  union { unsigned u; float f; } v; v.u = (b & 0xffffu) << 16;
  return v.f;
}
DEV void glds16(const ushort* g, ushort* l) {
  __builtin_amdgcn_global_load_lds(
      (const __attribute__((address_space(1))) unsigned int*)g,
      (__attribute__((address_space(3))) unsigned int*)l, 16, 0, 0);
}

__global__ __launch_bounds__(256) void cvt_all(const float* __restrict__ x,
                                               const float* __restrict__ Ww,
                                               const float* __restrict__ Ow,
                                               ushort* __restrict__ xb,
                                               ushort* __restrict__ wqkvb,
                                               ushort* __restrict__ outwb) {
  int i = blockIdx.x * 256 + threadIdx.x;
  const float* src; ushort* dst; int off;
  if (i < 1048576)      { src = x;  dst = xb;    off = i; }
  else if (i < 1835008) { src = Ww; dst = wqkvb; off = i - 1048576; }
  else                  { src = Ow; dst = outwb; off = i - 1835008; }
  float4 v = ((const float4*)src)[off];
  ushort4 o;
  o.x = f2bf(v.x); o.y = f2bf(v.y); o.z = f2bf(v.z); o.w = f2bf(v.w);
  ((ushort4*)dst)[off] = o;
}

// QKV: C = A[4096,1024]*Bw[3072,1024]^T + bias ; 128x128x32, identity staging.
template <bool OUT_BF16, bool KSCALE>
__global__ __launch_bounds__(256) void gemm_bt(const ushort* __restrict__ A,
                                               const ushort* __restrict__ Bw,
                                               const float* __restrict__ bias,
                                               void* __restrict__ Cout,
                                               int M, int N, int K) {
  __shared__ ushort As[128 * 32];
  __shared__ ushort Bs[128 * 32];
  const int t = threadIdx.x;
  const int wid = t >> 6, lane = t & 63;
  const int quad = lane >> 4, l16 = lane & 15;
  const int g = blockIdx.x;            // 768 = 8 XCD * 96
  const int j = g >> 3;
  const int bx = (g & 7) * 3 + j % 3;
  const int by = j / 3;
  const int bm = by * 128, bn = bx * 128;
  const int wm = (wid >> 1) * 64, wn = (wid & 1) * 64;

  f32x4 acc[4][4];
  const f32x4 z = {0.f, 0.f, 0.f, 0.f};
#pragma unroll
  for (int i = 0; i < 4; ++i)
#pragma unroll
    for (int jj = 0; jj < 4; ++jj) acc[i][jj] = z;

  const ushort* ag = A + (size_t)(bm + (t >> 2)) * K + ((t & 3) * 8);
  const ushort* bg = Bw + (size_t)(bn + (t >> 2)) * K + ((t & 3) * 8);
  ushort* asl = As + wid * 512;
  ushort* bsl = Bs + wid * 512;
  const size_t rowskip = (size_t)64 * K;

  for (int k0 = 0; k0 < K; k0 += 32) {
    glds16(ag + k0, asl);
    glds16(ag + k0 + rowskip, asl + 2048);
    glds16(bg + k0, bsl);
    glds16(bg + k0 + rowskip, bsl + 2048);
    __syncthreads();
    bf16x8 af[4], bf[4];
#pragma unroll
    for (int i = 0; i < 4; ++i) {
      af[i] = *(const bf16x8*)(As + (wm + i * 16 + l16) * 32 + quad * 8);
      bf[i] = *(const bf16x8*)(Bs + (wn + i * 16 + l16) * 32 + quad * 8);
    }
#pragma unroll
    for (int i = 0; i < 4; ++i)
#pragma unroll
      for (int jj = 0; jj < 4; ++jj)
        acc[i][jj] = __builtin_amdgcn_mfma_f32_16x16x32_bf16(af[i], bf[jj], acc[i][jj], 0, 0, 0);
    __syncthreads();
  }

#pragma unroll
  for (int i = 0; i < 4; ++i)
#pragma unroll
    for (int jj = 0; jj < 4; ++jj) {
      const int col = bn + wn + jj * 16 + l16;
      const float bv = bias[col];
      float sc = 1.f;
      if (KSCALE) sc = ((col >> 10) == 1) ? 0.125f : 1.f;
#pragma unroll
      for (int r = 0; r < 4; ++r) {
        const int row = bm + wm + i * 16 + quad * 4 + r;
        const float v = (acc[i][jj][r] + bv) * sc;
        if (OUT_BF16)
          ((ushort*)Cout)[(size_t)row * N + col] = f2bf(v);
        else
          ((float*)Cout)[(size_t)row * N + col] = v;
      }
    }
}

// Out projection: BM=64, BN=128, BK=32; grid 512; scalar fp32 epilogue.
__global__ __launch_bounds__(256) void gemm_out64(const ushort* __restrict__ A,
                                                  const ushort* __restrict__ Bw,
                                                  const float* __restrict__ bias,
                                                  float* __restrict__ C,
                                                  int M, int N, int K) {
  __shared__ ushort As[64 * 32];
  __shared__ ushort Bs[128 * 32];
  const int t = threadIdx.x;
  const int wid = t >> 6, lane = t & 63;
  const int quad = lane >> 4, l16 = lane & 15;
  const int g = blockIdx.x;
  const int bm = (g >> 3) * 64, bn = (g & 7) * 128;
  const int wn = wid * 32;

  f32x4 acc[4][2];
  const f32x4 z = {0.f, 0.f, 0.f, 0.f};
#pragma unroll
  for (int i = 0; i < 4; ++i) { acc[i][0] = z; acc[i][1] = z; }

  const ushort* ag = A + (size_t)(bm + (t >> 2)) * K + ((t & 3) * 8);
  const ushort* bg = Bw + (size_t)(bn + (t >> 2)) * K + ((t & 3) * 8);
  ushort* asl = As + wid * 512;
  ushort* bsl = Bs + wid * 512;
  const size_t rowskip = (size_t)64 * K;

  for (int k0 = 0; k0 < K; k0 += 32) {
    glds16(ag + k0, asl);
    glds16(bg + k0, bsl);
    glds16(bg + k0 + rowskip, bsl + 2048);
    __syncthreads();
    bf16x8 af[4], bf[2];
#pragma unroll
    for (int i = 0; i < 4; ++i)
      af[i] = *(const bf16x8*)(As + (i * 16 + l16) * 32 + quad * 8);
#pragma unroll
    for (int jj = 0; jj < 2; ++jj)
      bf[jj] = *(const bf16x8*)(Bs + (wn + jj * 16 + l16) * 32 + quad * 8);
#pragma unroll
    for (int i = 0; i < 4; ++i)
#pragma unroll
      for (int jj = 0; jj < 2; ++jj)
        acc[i][jj] = __builtin_amdgcn_mfma_f32_16x16x32_bf16(af[i], bf[jj], acc[i][jj], 0, 0, 0);
    __syncthreads();
  }

#pragma unroll
  for (int i = 0; i < 4; ++i)
#pragma unroll
    for (int jj = 0; jj < 2; ++jj) {
      const int col = bn + wn + jj * 16 + l16;
      const float bv = bias[col];
#pragma unroll
      for (int r = 0; r < 4; ++r) {
        const int row = bm + i * 16 + quad * 4 + r;
        C[(size_t)row * N + col] = acc[i][jj][r] + bv;
      }
    }
}

// Per-(bh,chunk) KV sums via MFMA + vT export:
// mlocT[bh][c][e][f] = sum_s v[s][e]*k[s][f]; vTg[bh][c][e:64][s:128] bf16.
__global__ __launch_bounds__(256) void kv_local(const ushort* __restrict__ qkv,
                                                float* __restrict__ mlocT,
                                                ushort* __restrict__ vTg) {
  const int c = blockIdx.x, bh = blockIdx.y;
  const int b = bh >> 4, hd = bh & 15;
  const int t = threadIdx.x;
  const int wid = t >> 6, lane = t & 63;
  const int quad = lane >> 4, l16 = lane & 15;
  __shared__ ushort kT[64 * 136];
  __shared__ ushort vT[64 * 136];

  {
    const int row = t & 127;
    const int isv = t >> 7;
    const ushort* gp = qkv + (size_t)(b * 2048 + c * 128 + row) * 3072 +
                       1024 + isv * 1024 + hd * 64;
    ushort tmp[64];
#pragma unroll
    for (int q = 0; q < 8; ++q) *(uint4*)(tmp + q * 8) = *(const uint4*)(gp + q * 8);
    ushort* dst = isv ? vT : kT;
#pragma unroll
    for (int j = 0; j < 64; ++j) dst[j * 136 + row] = tmp[j];
  }
  __syncthreads();

  {  // export vT -> vTg (coalesced)
    const int row = t >> 2, seg = t & 3;
    const ushort* src = vT + row * 136 + seg * 32;
    ushort* dst = vTg + ((size_t)bh * 16 + c) * 8192 + row * 128 + seg * 32;
#pragma unroll
    for (int q = 0; q < 4; ++q)
      *(uint4*)(dst + q * 8) = *(const uint4*)(src + q * 8);
  }

  const f32x4 z = {0.f, 0.f, 0.f, 0.f};
  f32x4 acc[4];
#pragma unroll
  for (int ct = 0; ct < 4; ++ct) acc[ct] = z;
#pragma unroll
  for (int kc = 0; kc < 4; ++kc) {
    bf16x8 afr = *(const bf16x8*)(vT + (wid * 16 + l16) * 136 + kc * 32 + quad * 8);
#pragma unroll
    for (int ct = 0; ct < 4; ++ct) {
      bf16x8 bfr = *(const bf16x8*)(kT + (ct * 16 + l16) * 136 + kc * 32 + quad * 8);
      acc[ct] = __builtin_amdgcn_mfma_f32_16x16x32_bf16(afr, bfr, acc[ct], 0, 0, 0);
    }
  }

  float* outp = mlocT + ((size_t)bh * 16 + c) * 4096;
#pragma unroll
  for (int ct = 0; ct < 4; ++ct)
#pragma unroll
    for (int r = 0; r < 4; ++r)
      outp[(wid * 16 + quad * 4 + r) * 64 + ct * 16 + l16] = acc[ct][r];
}

// Exclusive prefix over chunks, parallel over 4096 (e,f) entries per bh.
__global__ __launch_bounds__(256) void kv_prefix(const float* __restrict__ mlocT,
                                                 ushort* __restrict__ statesT) {
  const int slice = blockIdx.x, bh = blockIdx.y;
  const int eidx = slice * 256 + threadIdx.x;
  float run = 0.f;
  for (int c = 0; c < 16; ++c) {
    const size_t idx = ((size_t)bh * 16 + c) * 4096 + eidx;
    statesT[idx] = f2bf(run);
    run += mlocT[idx];
  }
}

// Per-(bh,chunk): P = tril(Q K^T) ; Y = P V + Q S_prefix.
// Balanced wave->row-tile map {wid, 7-wid}; V via glds16 from vTg; Y via LDS
// transpose. Zero-P prologue removed: the P-write loop runs tj <= (rt|1), and
// for tj=rt+1 every scol>row so it writes the zeros PV needs (pacc there is 0).
__global__ __launch_bounds__(256) void attn_chunk(const ushort* __restrict__ qkv,
                                                  const ushort* __restrict__ statesT,
                                                  const ushort* __restrict__ vTg,
                                                  ushort* __restrict__ yb) {
  const int c = blockIdx.x, bh = blockIdx.y;
  const int b = bh >> 4, hd = bh & 15;
  const int l0 = c * 128;
  const int t = threadIdx.x;
  const int wid = t >> 6, lane = t & 63;
  const int quad = lane >> 4, l16 = lane & 15;

  __shared__ ushort P[16384];  // [row][16B chunks] XOR by row&7 ; later Y [row][72]
  __shared__ ushort U[16384];
  ushort* Qs = U;              // [row:128][64] chunk^(row&7)
  ushort* Ks = U + 8192;
  ushort* vT = U;              // phase2: [e:64][s:128], chunk^(e&7)
  ushort* sT = U + 8704;       // phase2: [e:64][f:64] stride 72

  {  // stage Q,K swizzled
    const int kcs = ((lane & 7) ^ (lane >> 3)) * 8;
    const ushort* qg = qkv + (size_t)(b * 2048 + l0 + (t >> 3)) * 3072 + hd * 64 + kcs;
    ushort* ql = Qs + wid * 512;
    ushort* kl = Ks + wid * 512;
#pragma unroll
    for (int h2 = 0; h2 < 4; ++h2) {
      glds16(qg + (size_t)h2 * 32 * 3072, ql + h2 * 2048);
      glds16(qg + (size_t)h2 * 32 * 3072 + 1024, kl + h2 * 2048);
    }
  }
  __syncthreads();  // B1: Q,K landed

  bf16x8 qf[2][2];
#pragma unroll
  for (int i = 0; i < 2; ++i) {
    const int rt = (i == 0) ? wid : 7 - wid;
#pragma unroll
    for (int kc = 0; kc < 2; ++kc)
      qf[i][kc] = *(const bf16x8*)(Qs + (rt * 16 + l16) * 64 +
                                   (((kc * 4 + quad) ^ (l16 & 7)) * 8));
  }

  const f32x4 z4 = {0.f, 0.f, 0.f, 0.f};
  f32x4 pacc[2][8];
#pragma unroll
  for (int i = 0; i < 2; ++i)
#pragma unroll
    for (int jj = 0; jj < 8; ++jj) pacc[i][jj] = z4;

#pragma unroll
  for (int i = 0; i < 2; ++i) {
    const int rt = (i == 0) ? wid : 7 - wid;
#pragma unroll
    for (int tj = 0; tj < 8; ++tj) {
      if (tj <= rt) {
#pragma unroll
        for (int kc = 0; kc < 2; ++kc) {
          bf16x8 kfr = *(const bf16x8*)(Ks + (tj * 16 + l16) * 64 +
                                        (((kc * 4 + quad) ^ (l16 & 7)) * 8));
          pacc[i][tj] = __builtin_amdgcn_mfma_f32_16x16x32_bf16(qf[i][kc], kfr, pacc[i][tj], 0, 0, 0);
        }
      }
    }
  }
  __syncthreads();  // B2: phase-1 reads done; U reusable

  {  // stage V^T via glds16 from vTg
    const ushort* vgb = vTg + ((size_t)bh * 16 + c) * 8192;
#pragma unroll
    for (int h = 0; h < 4; ++h) {
      const int gch = (wid * 4 + h) * 64 + lane;
      const int e = gch >> 4;
      const int sc = (gch & 15) ^ (e & 7);
      glds16(vgb + e * 128 + sc * 8, vT + (wid * 4 + h) * 512);
    }
  }
#pragma unroll
  for (int i = 0; i < 2; ++i) {  // write masked P incl. boundary zeros (tj=rt+1)
    const int rt = (i == 0) ? wid : 7 - wid;
    const int tjmax = rt | 1;
#pragma unroll
    for (int tj = 0; tj < 8; ++tj) {
      if (tj <= tjmax) {
#pragma unroll
        for (int r = 0; r < 4; ++r) {
          const int row = rt * 16 + quad * 4 + r;
          const int scol = tj * 16 + l16;
          const float v = (scol <= row) ? pacc[i][tj][r] : 0.f;
          P[row * 128 + (((scol >> 3) ^ (row & 7)) * 8) + (scol & 7)] = f2bf(v);
        }
      }
    }
  }
  {  // stage state coalesced -> sT stride 72
    const ushort* sg = statesT + ((size_t)bh * 16 + c) * 4096;
#pragma unroll
    for (int h = 0; h < 2; ++h) {
      const int cc = h * 256 + t;
      uint4 d = *(const uint4*)(sg + cc * 8);
      *(uint4*)(sT + (cc >> 3) * 72 + (cc & 7) * 8) = d;
    }
  }
  __syncthreads();  // B3: P, vT, sT ready

  f32x4 yacc[2][4];
#pragma unroll
  for (int i = 0; i < 2; ++i)
#pragma unroll
    for (int jj = 0; jj < 4; ++jj) yacc[i][jj] = z4;

#pragma unroll
  for (int i = 0; i < 2; ++i) {
    const int rt = (i == 0) ? wid : 7 - wid;
    const int kcmax = rt >> 1;
#pragma unroll
    for (int kc = 0; kc < 4; ++kc) {
      if (kc <= kcmax) {
        const int prow = rt * 16 + l16;
        bf16x8 pf;
        *(uint4*)&pf = *(const uint4*)(P + prow * 128 + (((kc * 4 + quad) ^ (prow & 7)) * 8));
#pragma unroll
        for (int ct = 0; ct < 4; ++ct) {
          const int e = ct * 16 + l16;
          bf16x8 vf = *(const bf16x8*)(vT + e * 128 + (((kc * 4 + quad) ^ (e & 7)) * 8));
          yacc[i][ct] = __builtin_amdgcn_mfma_f32_16x16x32_bf16(pf, vf, yacc[i][ct], 0, 0, 0);
        }
      }
    }
#pragma unroll
    for (int kc = 0; kc < 2; ++kc) {
#pragma unroll
      for (int ct = 0; ct < 4; ++ct) {
        bf16x8 sf = *(const bf16x8*)(sT + (ct * 16 + l16) * 72 + kc * 32 + quad * 8);
        yacc[i][ct] = __builtin_amdgcn_mfma_f32_16x16x32_bf16(qf[i][kc], sf, yacc[i][ct], 0, 0, 0);
      }
    }
  }
  __syncthreads();  // B4: P reads done; reuse P as Y buffer

#pragma unroll
  for (int i = 0; i < 2; ++i) {  // Y -> LDS [row:128][64] stride 72
    const int rt = (i == 0) ? wid : 7 - wid;
#pragma unroll
    for (int ct = 0; ct < 4; ++ct)
#pragma unroll
      for (int r = 0; r < 4; ++r)
        P[(rt * 16 + quad * 4 + r) * 72 + ct * 16 + l16] = f2bf(yacc[i][ct][r]);
  }
  __syncthreads();  // B5

  {  // coalesced Y store
    const int row = t >> 1, seg = t & 1;
    const ushort* src = P + row * 72 + seg * 32;
    ushort* dst = yb + (size_t)(b * 2048 + l0 + row) * 1024 + hd * 64 + seg * 32;
#pragma unroll
    for (int q = 0; q < 4; ++q)
      *(uint4*)(dst + q * 8) = *(const uint4*)(src + q * 8);
  }
}

extern "C" void kernel_launch(void* const* d_in, const int* in_sizes, int n_in,
                              void* d_out, int out_size, void* d_ws, size_t ws_size,
                              hipStream_t stream) {
  const float* x  = (const float*)d_in[0];
  const float* Ww = (const float*)d_in[1];
  const float* Wb = (const float*)d_in[2];
  const float* Ow = (const float*)d_in[3];
  const float* Ob = (const float*)d_in[4];
  float* out = (float*)d_out;

  char* ws = (char*)d_ws;
  ushort* xb      = (ushort*)(ws);                              // dead after QKV GEMM
  ushort* vTg     = (ushort*)(ws);                              // reuses xb region
  ushort* wqkvb   = (ushort*)(ws + (size_t)8  * 1024 * 1024);
  ushort* outwb   = (ushort*)(ws + (size_t)14 * 1024 * 1024);
  ushort* qkvb    = (ushort*)(ws + (size_t)16 * 1024 * 1024);
  float*  mlocT   = (float*) (ws + (size_t)40 * 1024 * 1024);
  ushort* statesT = (ushort*)(ws + (size_t)48 * 1024 * 1024);
  ushort* yb      = (ushort*)(ws + (size_t)52 * 1024 * 1024);

  cvt_all<<<8192, 256, 0, stream>>>(x, Ww, Ow, xb, wqkvb, outwb);
  gemm_bt<true, true><<<768, 256, 0, stream>>>(xb, wqkvb, Wb, (void*)qkvb, 4096, 3072, 1024);
  kv_local<<<dim3(16, 32), 256, 0, stream>>>(qkvb, mlocT, vTg);
  kv_prefix<<<dim3(16, 32), 256, 0, stream>>>(mlocT, statesT);
  attn_chunk<<<dim3(16, 32), 256, 0, stream>>>(qkvb, statesT, vTg, yb);
  gemm_out64<<<512, 256, 0, stream>>>(yb, outwb, Ob, out, 4096, 1024, 1024);
}